// Round 1
// baseline (1093.829 us; speedup 1.0000x reference)
//
#include <hip/hip_runtime.h>
#include <math.h>

#define SN  512
#define NN  128
#define CIN 32
#define CC  4    // used relation channels
#define CA  5    // stored channels (last one dropped)
#define HH  64   // h1 == h2 == 64
#define YY  96   // h + cin
#define H3  128
#define H4  64
#define EPSF 1e-7f

// conv1: grid (512, 4), block 256 (4 waves); each wave owns 8 rows.
// Phase 1: per row i, per lane (a = lane&31, cp = lane>>5):
//   M_un[a,c] = sum_j A[s,i,j,c]*x[s,j,a], S[c] = sum_j A  (c = 2cp, 2cp+1)
//   normalize M by 1/(S+eps), stash in LDS.
// Phase 2: lane = output channel b; batch 8 rows per W read.
__global__ __launch_bounds__(256) void conv1_kernel(
    const float* __restrict__ A, const float* __restrict__ x,
    const float* __restrict__ W, const float* __restrict__ LW,
    const float* __restrict__ LB, float* __restrict__ y)
{
    __shared__ float xs[NN*CIN];        // 16 KB, [j][a]
    __shared__ float Mw[4][8][CC*CIN];  // 16 KB, per-wave M for 8 rows
    const int s   = blockIdx.x;
    const int i0  = blockIdx.y * 32;
    const int tid = threadIdx.x;
    const int wave = tid >> 6, lane = tid & 63;

    for (int t = tid; t < NN*CIN; t += 256) {
        float v = x[(size_t)s*NN*CIN + t];
        xs[t] = v;
        int j = t >> 5, a = t & 31;
        y[((size_t)s*NN + j)*YY + HH + a] = v;   // x-part of y = [h1 | x]
    }
    __syncthreads();

    const int a = lane & 31, cp = lane >> 5;
    for (int r = 0; r < 8; ++r) {
        const int i = i0 + wave*8 + r;
        const float* Arow = A + ((size_t)(s*NN + i))*NN*CA + 2*cp;
        float m0 = 0.f, m1 = 0.f, s0 = 0.f, s1 = 0.f;
        #pragma unroll 4
        for (int j = 0; j < NN; ++j) {
            float a0 = Arow[j*CA];
            float a1 = Arow[j*CA + 1];
            float xv = xs[j*CIN + a];
            m0 += a0*xv; m1 += a1*xv; s0 += a0; s1 += a1;
        }
        Mw[wave][r][(2*cp  )*CIN + a] = m0 * (1.0f/(s0 + EPSF));
        Mw[wave][r][(2*cp+1)*CIN + a] = m1 * (1.0f/(s1 + EPSF));
    }
    __syncthreads();

    const int b = lane;                 // 64 output channels
    float lbv = LB[b];
    float acc[8];
    #pragma unroll
    for (int r = 0; r < 8; ++r) acc[r] = lbv;
    for (int c = 0; c < CC; ++c) {
        #pragma unroll 4
        for (int aa = 0; aa < CIN; ++aa) {
            float w = W[(aa*HH + b)*CC + c];
            float mv;
            #pragma unroll
            for (int r = 0; r < 8; ++r) {
                mv = Mw[wave][r][c*CIN + aa];
                acc[r] += mv * w;
            }
        }
    }
    #pragma unroll 4
    for (int aa = 0; aa < CIN; ++aa) {
        float w = LW[aa*HH + b];
        #pragma unroll
        for (int r = 0; r < 8; ++r)
            acc[r] += xs[(i0 + wave*8 + r)*CIN + aa] * w;
    }
    #pragma unroll
    for (int r = 0; r < 8; ++r) {
        const int i = i0 + wave*8 + r;
        y[((size_t)s*NN + i)*YY + b] = tanhf(acc[r]);
    }
}

// conv2: input y = [h1 | x] (96 ch). grid (512, 2), block 512 (8 waves),
// each wave owns 8 rows; lane covers 3 input channels x 2 relation channels.
__global__ __launch_bounds__(512) void conv2_kernel(
    const float* __restrict__ A, const float* __restrict__ y,
    const float* __restrict__ W, const float* __restrict__ LW,
    const float* __restrict__ LB, float* __restrict__ h2)
{
    __shared__ float ys[NN*YY];         // 48 KB
    __shared__ float Mw[8][8][CC*YY];   // 96 KB
    const int s   = blockIdx.x;
    const int i0  = blockIdx.y * 64;
    const int tid = threadIdx.x;
    const int wave = tid >> 6, lane = tid & 63;

    for (int t = tid; t < NN*YY; t += 512)
        ys[t] = y[(size_t)s*NN*YY + t];
    __syncthreads();

    const int a = lane & 31, cp = lane >> 5;
    for (int r = 0; r < 8; ++r) {
        const int i = i0 + wave*8 + r;
        const float* Arow = A + ((size_t)(s*NN + i))*NN*CA + 2*cp;
        float m00=0,m01=0,m10=0,m11=0,m20=0,m21=0,s0=0,s1=0;
        #pragma unroll 2
        for (int j = 0; j < NN; ++j) {
            float a0 = Arow[j*CA];
            float a1 = Arow[j*CA + 1];
            float x0 = ys[j*YY + a];
            float x1 = ys[j*YY + 32 + a];
            float x2 = ys[j*YY + 64 + a];
            m00 += a0*x0; m10 += a0*x1; m20 += a0*x2;
            m01 += a1*x0; m11 += a1*x1; m21 += a1*x2;
            s0  += a0;    s1  += a1;
        }
        float n0 = 1.0f/(s0 + EPSF), n1 = 1.0f/(s1 + EPSF);
        Mw[wave][r][(2*cp  )*YY +      a] = m00*n0;
        Mw[wave][r][(2*cp  )*YY + 32 + a] = m10*n0;
        Mw[wave][r][(2*cp  )*YY + 64 + a] = m20*n0;
        Mw[wave][r][(2*cp+1)*YY +      a] = m01*n1;
        Mw[wave][r][(2*cp+1)*YY + 32 + a] = m11*n1;
        Mw[wave][r][(2*cp+1)*YY + 64 + a] = m21*n1;
    }
    __syncthreads();

    const int b = lane;
    float lbv = LB[b];
    float acc[8];
    #pragma unroll
    for (int r = 0; r < 8; ++r) acc[r] = lbv;
    for (int c = 0; c < CC; ++c) {
        #pragma unroll 4
        for (int aa = 0; aa < YY; ++aa) {
            float w = W[(aa*HH + b)*CC + c];
            #pragma unroll
            for (int r = 0; r < 8; ++r)
                acc[r] += Mw[wave][r][c*YY + aa] * w;
        }
    }
    #pragma unroll 4
    for (int aa = 0; aa < YY; ++aa) {
        float w = LW[aa*HH + b];
        #pragma unroll
        for (int r = 0; r < 8; ++r)
            acc[r] += ys[(i0 + wave*8 + r)*YY + aa] * w;
    }
    #pragma unroll
    for (int r = 0; r < 8; ++r) {
        const int i = i0 + wave*8 + r;
        h2[((size_t)s*NN + i)*HH + b] = tanhf(acc[r]);
    }
}

// pool + MLP head: one block (128 threads) per sample.
__global__ __launch_bounds__(128) void pool_kernel(
    const float* __restrict__ h2, const float* __restrict__ x,
    const float* __restrict__ gw, const float* __restrict__ gb,
    const float* __restrict__ nw, const float* __restrict__ nb,
    const float* __restrict__ l3w, const float* __restrict__ l3b,
    const float* __restrict__ l4w, const float* __restrict__ l4b,
    const float* __restrict__ l5w, const float* __restrict__ l5b,
    float* __restrict__ out)
{
    __shared__ float xc[NN][YY+1];   // +1 pad: kills 32-way conflicts on row reads
    __shared__ float gate[NN];
    __shared__ float red[NN];
    __shared__ float tmp[NN];
    const int s = blockIdx.x, tid = threadIdx.x;

    for (int t = tid; t < NN*HH; t += 128)
        xc[t >> 6][t & 63] = h2[(size_t)s*NN*HH + t];
    for (int t = tid; t < NN*CIN; t += 128)
        xc[t >> 5][HH + (t & 31)] = x[(size_t)s*NN*CIN + t];
    __syncthreads();

    // gate logits, thread = node i
    float z = gb[0];
    for (int a = 0; a < YY; ++a) z += xc[tid][a] * gw[a];
    red[tid] = z;
    __syncthreads();
    for (int off = 64; off > 0; off >>= 1) {
        if (tid < off) red[tid] = fmaxf(red[tid], red[tid + off]);
        __syncthreads();
    }
    const float zmax = red[0];
    __syncthreads();
    const float e = expf(z - zmax);
    red[tid] = e;
    __syncthreads();
    for (int off = 64; off > 0; off >>= 1) {
        if (tid < off) red[tid] += red[tid + off];
        __syncthreads();
    }
    const float gsum = red[0];
    __syncthreads();
    gate[tid] = e / gsum;
    __syncthreads();

    // pooled[b] = sum_i gate[i] * tanh(sum_a xc[i][a]*nw[a][b] + nb[b])
    const int b = tid;
    const float nbv = nb[b];
    float acc = 0.f;
    for (int ic = 0; ic < NN; ic += 16) {
        float t[16];
        #pragma unroll
        for (int r = 0; r < 16; ++r) t[r] = nbv;
        for (int a = 0; a < YY; ++a) {
            float w = nw[a*H3 + b];
            #pragma unroll
            for (int r = 0; r < 16; ++r)
                t[r] += xc[ic + r][a] * w;
        }
        #pragma unroll
        for (int r = 0; r < 16; ++r)
            acc += gate[ic + r] * tanhf(t[r]);
    }
    tmp[tid] = tanhf(acc);          // h3
    __syncthreads();
    float a4 = l3b[tid];
    for (int aa = 0; aa < H3; ++aa) a4 += tmp[aa] * l3w[aa*H3 + tid];
    const float h4v = tanhf(a4);
    __syncthreads();
    tmp[tid] = h4v;
    __syncthreads();
    float h5v = 0.f;
    if (tid < H4) {
        float a5 = l4b[tid];
        for (int aa = 0; aa < H3; ++aa) a5 += tmp[aa] * l4w[aa*H4 + tid];
        h5v = tanhf(a5);
    }
    __syncthreads();
    if (tid < H4) tmp[tid] = h5v;
    __syncthreads();
    if (tid == 0) {
        float zo = l5b[0];
        for (int aa = 0; aa < H4; ++aa) zo += tmp[aa] * l5w[aa];
        out[s] = 1.0f / (1.0f + expf(-zo));
    }
}

extern "C" void kernel_launch(void* const* d_in, const int* in_sizes, int n_in,
                              void* d_out, int out_size, void* d_ws, size_t ws_size,
                              hipStream_t stream)
{
    const float* A   = (const float*)d_in[0];
    const float* x   = (const float*)d_in[1];
    const float* w1  = (const float*)d_in[2];
    const float* lw1 = (const float*)d_in[3];
    const float* lb1 = (const float*)d_in[4];
    const float* w2  = (const float*)d_in[5];
    const float* lw2 = (const float*)d_in[6];
    const float* lb2 = (const float*)d_in[7];
    const float* gw  = (const float*)d_in[8];
    const float* gb  = (const float*)d_in[9];
    const float* nw  = (const float*)d_in[10];
    const float* nb  = (const float*)d_in[11];
    const float* l3w = (const float*)d_in[12];
    const float* l3b = (const float*)d_in[13];
    const float* l4w = (const float*)d_in[14];
    const float* l4b = (const float*)d_in[15];
    const float* l5w = (const float*)d_in[16];
    const float* l5b = (const float*)d_in[17];
    float* out = (float*)d_out;

    float* ws_y  = (float*)d_ws;                    // [512][128][96] f32, 25.2 MB
    float* ws_h2 = ws_y + (size_t)SN*NN*YY;         // [512][128][64] f32, 16.8 MB

    conv1_kernel<<<dim3(SN, 4), 256, 0, stream>>>(A, x, w1, lw1, lb1, ws_y);
    conv2_kernel<<<dim3(SN, 2), 512, 0, stream>>>(A, ws_y, w2, lw2, lb2, ws_h2);
    pool_kernel<<<SN, 128, 0, stream>>>(ws_h2, x, gw, gb, nw, nb,
                                        l3w, l3b, l4w, l4b, l5w, l5b, out);
}

// Round 2
// 212.525 us; speedup vs baseline: 5.1468x; 5.1468x over previous
//
#include <hip/hip_runtime.h>
#include <math.h>

#define SN  512
#define NN  128
#define CIN 32
#define CC  4
#define CA  5
#define HH  64
#define YY  96
#define H3  128
#define H4  64
#define EPSF 1e-7f

typedef __attribute__((ext_vector_type(8))) short  bf16x8;
typedef __attribute__((ext_vector_type(4))) float  f32x4;
typedef __attribute__((ext_vector_type(4))) unsigned short us4;

__device__ inline unsigned short f2b(float f) {
    unsigned u = __builtin_bit_cast(unsigned, f);
    return (unsigned short)((u + 0x7FFFu + ((u >> 16) & 1u)) >> 16);
}
__device__ inline float b2f(unsigned short h) {
    unsigned u = ((unsigned)h) << 16;
    return __builtin_bit_cast(float, u);
}

// One block per sample, 512 threads (8 waves).
// Phase 1: stage W (+LW as channel 4) transposed to LDS bf16: Wb[c][b][a].
// Phase 2: P_c = y @ W_c per sample via MFMA (wave w owns j-rows [16w,16w+16));
//          y fragments read directly from global (h1 ws + x, or x). P -> LDS
//          bf16 as Pb[c][b][j] (j contiguous = K-dim of the main GEMM).
// Phase 4: out_c[i,b] = sum_j A_c[i,j] * P_c[j,b]; A fragments converted
//          bf16 on the fly from global. Extra ones-B-fragment tile per c
//          computes rowsums S[i,c] in the same accumulator layout ->
//          normalize in-register, add P4 (linear term) + bias, tanh, store.
template<int CINY>
__global__ __launch_bounds__(512) void conv_mfma(
    const float* __restrict__ A, const float* __restrict__ xin,
    const float* __restrict__ h1in,
    const float* __restrict__ W, const float* __restrict__ LW,
    const float* __restrict__ LB, float* __restrict__ out)
{
    constexpr int K32  = CINY / 32;     // k-steps of the P GEMM
    constexpr int WROW = CINY + 8;      // padded Wb row (bf16 elems), 16B-aligned rows
    __shared__ unsigned short WbL[5 * 64 * WROW];
    __shared__ unsigned short PbL[5 * 64 * 136];   // [c][b][j(128)+8 pad]

    const int s    = blockIdx.x;
    const int tid  = threadIdx.x;
    const int wave = tid >> 6, lane = tid & 63;
    const int lm   = lane & 15, kg = lane >> 4;

    // ---- Phase 1: stage weights (transpose W[a][b][c] -> Wb[c][b][a]) ----
    for (int t = tid; t < CINY * 64 * 4; t += 512) {
        int c = t & 3, b = (t >> 2) & 63, a = t >> 8;
        WbL[(c * 64 + b) * WROW + a] = f2b(W[t]);
    }
    for (int t = tid; t < CINY * 64; t += 512) {
        int b = t & 63, a = t >> 6;
        WbL[(256 + b) * WROW + a] = f2b(LW[t]);
    }
    __syncthreads();

    // ---- Phase 2: P GEMM ----
    {
        const int jrow = wave * 16 + lm;
        bf16x8 af[K32];
        #pragma unroll
        for (int ks = 0; ks < K32; ++ks) {
            int a0 = ks * 32 + kg * 8;
            const float* src;
            if constexpr (CINY == 96) {
                if (a0 < 64) src = h1in + ((size_t)s * NN + jrow) * HH + a0;
                else         src = xin  + ((size_t)s * NN + jrow) * CIN + (a0 - 64);
            } else {
                src = xin + ((size_t)s * NN + jrow) * CIN + a0;
            }
            float4 f0 = *(const float4*)src;
            float4 f1 = *(const float4*)(src + 4);
            bf16x8 v;
            v[0] = (short)f2b(f0.x); v[1] = (short)f2b(f0.y);
            v[2] = (short)f2b(f0.z); v[3] = (short)f2b(f0.w);
            v[4] = (short)f2b(f1.x); v[5] = (short)f2b(f1.y);
            v[6] = (short)f2b(f1.z); v[7] = (short)f2b(f1.w);
            af[ks] = v;
        }
        for (int c = 0; c < 5; ++c) {
            f32x4 pc[4];
            #pragma unroll
            for (int n = 0; n < 4; ++n) pc[n] = (f32x4){0.f, 0.f, 0.f, 0.f};
            #pragma unroll
            for (int ks = 0; ks < K32; ++ks) {
                #pragma unroll
                for (int n = 0; n < 4; ++n) {
                    const bf16x8 bf = *(const bf16x8*)&WbL[(c * 64 + n * 16 + lm) * WROW + ks * 32 + kg * 8];
                    pc[n] = __builtin_amdgcn_mfma_f32_16x16x32_bf16(af[ks], bf, pc[n], 0, 0, 0);
                }
            }
            const int j0 = wave * 16 + kg * 4;
            #pragma unroll
            for (int n = 0; n < 4; ++n) {
                int b = n * 16 + lm;
                us4 w;
                w[0] = f2b(pc[n][0]); w[1] = f2b(pc[n][1]);
                w[2] = f2b(pc[n][2]); w[3] = f2b(pc[n][3]);
                *(us4*)&PbL[(c * 64 + b) * 136 + j0] = w;
            }
        }
    }
    __syncthreads();

    // ---- Phase 4: main GEMM over A ----
    {
        const int i0   = wave * 16;
        const int irow = i0 + lm;
        f32x4 acc[4][5];
        #pragma unroll
        for (int c = 0; c < 4; ++c)
            #pragma unroll
            for (int n = 0; n < 5; ++n) acc[c][n] = (f32x4){0.f, 0.f, 0.f, 0.f};
        bf16x8 ones;
        #pragma unroll
        for (int q = 0; q < 8; ++q) ones[q] = (short)0x3F80;

        for (int jt = 0; jt < 4; ++jt) {
            #pragma unroll
            for (int c = 0; c < 4; ++c) {
                const float* ap = A + (((size_t)s * NN + irow) * NN + jt * 32 + kg * 8) * CA + c;
                bf16x8 afr;
                #pragma unroll
                for (int q = 0; q < 8; ++q) afr[q] = (short)f2b(ap[q * CA]);
                #pragma unroll
                for (int n = 0; n < 4; ++n) {
                    const bf16x8 bf = *(const bf16x8*)&PbL[(c * 64 + n * 16 + lm) * 136 + jt * 32 + kg * 8];
                    acc[c][n] = __builtin_amdgcn_mfma_f32_16x16x32_bf16(afr, bf, acc[c][n], 0, 0, 0);
                }
                acc[c][4] = __builtin_amdgcn_mfma_f32_16x16x32_bf16(afr, ones, acc[c][4], 0, 0, 0);
            }
        }

        float inv[4][4];
        #pragma unroll
        for (int c = 0; c < 4; ++c)
            #pragma unroll
            for (int r = 0; r < 4; ++r) inv[c][r] = 1.0f / (acc[c][4][r] + EPSF);

        #pragma unroll
        for (int n = 0; n < 4; ++n) {
            const int b  = n * 16 + lm;
            const float lb = LB[b];
            #pragma unroll
            for (int r = 0; r < 4; ++r) {
                const int i = i0 + kg * 4 + r;
                float v = lb;
                #pragma unroll
                for (int c = 0; c < 4; ++c) v += acc[c][n][r] * inv[c][r];
                v += b2f(PbL[(256 + b) * 136 + i]);   // linear term y@LW
                out[((size_t)s * NN + i) * HH + b] = tanhf(v);
            }
        }
    }
}

// pool + MLP head: one block (128 threads) per sample. (unchanged, verified)
__global__ __launch_bounds__(128) void pool_kernel(
    const float* __restrict__ h2, const float* __restrict__ x,
    const float* __restrict__ gw, const float* __restrict__ gb,
    const float* __restrict__ nw, const float* __restrict__ nb,
    const float* __restrict__ l3w, const float* __restrict__ l3b,
    const float* __restrict__ l4w, const float* __restrict__ l4b,
    const float* __restrict__ l5w, const float* __restrict__ l5b,
    float* __restrict__ out)
{
    __shared__ float xc[NN][YY + 1];
    __shared__ float gate[NN];
    __shared__ float red[NN];
    __shared__ float tmp[NN];
    const int s = blockIdx.x, tid = threadIdx.x;

    for (int t = tid; t < NN * HH; t += 128)
        xc[t >> 6][t & 63] = h2[(size_t)s * NN * HH + t];
    for (int t = tid; t < NN * CIN; t += 128)
        xc[t >> 5][HH + (t & 31)] = x[(size_t)s * NN * CIN + t];
    __syncthreads();

    float z = gb[0];
    for (int a = 0; a < YY; ++a) z += xc[tid][a] * gw[a];
    red[tid] = z;
    __syncthreads();
    for (int off = 64; off > 0; off >>= 1) {
        if (tid < off) red[tid] = fmaxf(red[tid], red[tid + off]);
        __syncthreads();
    }
    const float zmax = red[0];
    __syncthreads();
    const float e = expf(z - zmax);
    red[tid] = e;
    __syncthreads();
    for (int off = 64; off > 0; off >>= 1) {
        if (tid < off) red[tid] += red[tid + off];
        __syncthreads();
    }
    const float gsum = red[0];
    __syncthreads();
    gate[tid] = e / gsum;
    __syncthreads();

    const int b = tid;
    const float nbv = nb[b];
    float acc = 0.f;
    for (int ic = 0; ic < NN; ic += 16) {
        float t[16];
        #pragma unroll
        for (int r = 0; r < 16; ++r) t[r] = nbv;
        for (int a = 0; a < YY; ++a) {
            float w = nw[a * H3 + b];
            #pragma unroll
            for (int r = 0; r < 16; ++r)
                t[r] += xc[ic + r][a] * w;
        }
        #pragma unroll
        for (int r = 0; r < 16; ++r)
            acc += gate[ic + r] * tanhf(t[r]);
    }
    tmp[tid] = tanhf(acc);
    __syncthreads();
    float a4 = l3b[tid];
    for (int aa = 0; aa < H3; ++aa) a4 += tmp[aa] * l3w[aa * H3 + tid];
    const float h4v = tanhf(a4);
    __syncthreads();
    tmp[tid] = h4v;
    __syncthreads();
    float h5v = 0.f;
    if (tid < H4) {
        float a5 = l4b[tid];
        for (int aa = 0; aa < H3; ++aa) a5 += tmp[aa] * l4w[aa * H4 + tid];
        h5v = tanhf(a5);
    }
    __syncthreads();
    if (tid < H4) tmp[tid] = h5v;
    __syncthreads();
    if (tid == 0) {
        float zo = l5b[0];
        for (int aa = 0; aa < H4; ++aa) zo += tmp[aa] * l5w[aa];
        out[s] = 1.0f / (1.0f + expf(-zo));
    }
}

extern "C" void kernel_launch(void* const* d_in, const int* in_sizes, int n_in,
                              void* d_out, int out_size, void* d_ws, size_t ws_size,
                              hipStream_t stream)
{
    const float* A   = (const float*)d_in[0];
    const float* x   = (const float*)d_in[1];
    const float* w1  = (const float*)d_in[2];
    const float* lw1 = (const float*)d_in[3];
    const float* lb1 = (const float*)d_in[4];
    const float* w2  = (const float*)d_in[5];
    const float* lw2 = (const float*)d_in[6];
    const float* lb2 = (const float*)d_in[7];
    const float* gw  = (const float*)d_in[8];
    const float* gb  = (const float*)d_in[9];
    const float* nw  = (const float*)d_in[10];
    const float* nb  = (const float*)d_in[11];
    const float* l3w = (const float*)d_in[12];
    const float* l3b = (const float*)d_in[13];
    const float* l4w = (const float*)d_in[14];
    const float* l4b = (const float*)d_in[15];
    const float* l5w = (const float*)d_in[16];
    const float* l5b = (const float*)d_in[17];
    float* out = (float*)d_out;

    float* ws_h1 = (float*)d_ws;                    // [512][128][64] f32
    float* ws_h2 = ws_h1 + (size_t)SN * NN * HH;    // [512][128][64] f32

    conv_mfma<32><<<SN, 512, 0, stream>>>(A, x, x,     w1, lw1, lb1, ws_h1);
    conv_mfma<96><<<SN, 512, 0, stream>>>(A, x, ws_h1, w2, lw2, lb2, ws_h2);
    pool_kernel<<<SN, 128, 0, stream>>>(ws_h2, x, gw, gb, nw, nb,
                                        l3w, l3b, l4w, l4b, l5w, l5b, out);
}

// Round 3
// 194.042 us; speedup vs baseline: 5.6371x; 1.0953x over previous
//
#include <hip/hip_runtime.h>
#include <math.h>

#define SN  512
#define NN  128
#define CIN 32
#define CA  5
#define HH  64
#define YY  96
#define H3  128
#define H4  64
#define EPSF 1e-7f

typedef __attribute__((ext_vector_type(8))) short  bf16x8;
typedef __attribute__((ext_vector_type(4))) float  f32x4;
typedef __attribute__((ext_vector_type(4))) unsigned short us4;

__device__ inline unsigned short f2b(float f) {
    unsigned u = __builtin_bit_cast(unsigned, f);
    return (unsigned short)((u + 0x7FFFu + ((u >> 16) & 1u)) >> 16);
}
__device__ inline float b2f(unsigned short h) {
    unsigned u = ((unsigned)h) << 16;
    return __builtin_bit_cast(float, u);
}

// One conv stage: stage W (+LW as ch4) -> LDS bf16, P_c = y@W_c via MFMA,
// then main GEMM over A with ones-trick rowsums; returns v[n][r] = tanh(out).
// b = n*16+lm, i = wave*16 + kg*4 + r.
template<int CINY>
__device__ __forceinline__ void conv_stage(
    const float* __restrict__ A, const float* __restrict__ xin,
    const float* __restrict__ h1in,
    const float* __restrict__ W, const float* __restrict__ LW,
    const float* __restrict__ LB,
    unsigned short* WbL, unsigned short* PbL,
    int s, int tid, float v[4][4])
{
    constexpr int K32  = CINY / 32;
    constexpr int WROW = CINY + 8;
    const int wave = tid >> 6, lane = tid & 63;
    const int lm = lane & 15, kg = lane >> 4;

    // ---- stage weights: W[a][b][c] -> WbL[c][b][a], LW -> channel 4 ----
    for (int t = tid; t < CINY * 64 * 4; t += 512) {
        int c = t & 3, b = (t >> 2) & 63, a = t >> 8;
        WbL[(c * 64 + b) * WROW + a] = f2b(W[t]);
    }
    for (int t = tid; t < CINY * 64; t += 512) {
        int b = t & 63, a = t >> 6;
        WbL[(256 + b) * WROW + a] = f2b(LW[t]);
    }
    __syncthreads();

    // ---- P GEMM: P_c[j,b] = sum_a y[j,a] W_c[a,b]; wave owns 16 j-rows ----
    {
        const int jrow = wave * 16 + lm;
        bf16x8 af[K32];
        #pragma unroll
        for (int ks = 0; ks < K32; ++ks) {
            int a0 = ks * 32 + kg * 8;
            const float* src;
            if constexpr (CINY == 96) {
                if (a0 < 64) src = h1in + ((size_t)s * NN + jrow) * HH + a0;
                else         src = xin  + ((size_t)s * NN + jrow) * CIN + (a0 - 64);
            } else {
                src = xin + ((size_t)s * NN + jrow) * CIN + a0;
            }
            float4 f0 = *(const float4*)src;
            float4 f1 = *(const float4*)(src + 4);
            bf16x8 vv;
            vv[0] = (short)f2b(f0.x); vv[1] = (short)f2b(f0.y);
            vv[2] = (short)f2b(f0.z); vv[3] = (short)f2b(f0.w);
            vv[4] = (short)f2b(f1.x); vv[5] = (short)f2b(f1.y);
            vv[6] = (short)f2b(f1.z); vv[7] = (short)f2b(f1.w);
            af[ks] = vv;
        }
        for (int c = 0; c < 5; ++c) {
            f32x4 pc[4];
            #pragma unroll
            for (int n = 0; n < 4; ++n) pc[n] = (f32x4){0.f, 0.f, 0.f, 0.f};
            #pragma unroll
            for (int ks = 0; ks < K32; ++ks) {
                #pragma unroll
                for (int n = 0; n < 4; ++n) {
                    const bf16x8 bf = *(const bf16x8*)&WbL[(c * 64 + n * 16 + lm) * WROW + ks * 32 + kg * 8];
                    pc[n] = __builtin_amdgcn_mfma_f32_16x16x32_bf16(af[ks], bf, pc[n], 0, 0, 0);
                }
            }
            const int j0 = wave * 16 + kg * 4;
            #pragma unroll
            for (int n = 0; n < 4; ++n) {
                int b = n * 16 + lm;
                us4 w;
                w[0] = f2b(pc[n][0]); w[1] = f2b(pc[n][1]);
                w[2] = f2b(pc[n][2]); w[3] = f2b(pc[n][3]);
                *(us4*)&PbL[(c * 64 + b) * 136 + j0] = w;
            }
        }
    }
    __syncthreads();

    // ---- main GEMM over A (+ ones-trick rowsums), normalize, tanh ----
    {
        const int i0   = wave * 16;
        const int irow = i0 + lm;
        f32x4 acc[4][5];
        #pragma unroll
        for (int c = 0; c < 4; ++c)
            #pragma unroll
            for (int n = 0; n < 5; ++n) acc[c][n] = (f32x4){0.f, 0.f, 0.f, 0.f};
        bf16x8 ones;
        #pragma unroll
        for (int q = 0; q < 8; ++q) ones[q] = (short)0x3F80;

        for (int jt = 0; jt < 4; ++jt) {
            #pragma unroll
            for (int c = 0; c < 4; ++c) {
                const float* ap = A + (((size_t)s * NN + irow) * NN + jt * 32 + kg * 8) * CA + c;
                bf16x8 afr;
                #pragma unroll
                for (int q = 0; q < 8; ++q) afr[q] = (short)f2b(ap[q * CA]);
                #pragma unroll
                for (int n = 0; n < 4; ++n) {
                    const bf16x8 bf = *(const bf16x8*)&PbL[(c * 64 + n * 16 + lm) * 136 + jt * 32 + kg * 8];
                    acc[c][n] = __builtin_amdgcn_mfma_f32_16x16x32_bf16(afr, bf, acc[c][n], 0, 0, 0);
                }
                acc[c][4] = __builtin_amdgcn_mfma_f32_16x16x32_bf16(afr, ones, acc[c][4], 0, 0, 0);
            }
        }

        float inv[4][4];
        #pragma unroll
        for (int c = 0; c < 4; ++c)
            #pragma unroll
            for (int r = 0; r < 4; ++r) inv[c][r] = 1.0f / (acc[c][4][r] + EPSF);

        #pragma unroll
        for (int n = 0; n < 4; ++n) {
            const int b  = n * 16 + lm;
            const float lb = LB[b];
            #pragma unroll
            for (int r = 0; r < 4; ++r) {
                const int i = i0 + kg * 4 + r;
                float vv = lb;
                #pragma unroll
                for (int c = 0; c < 4; ++c) vv += acc[c][n][r] * inv[c][r];
                vv += b2f(PbL[(256 + b) * 136 + i]);
                v[n][r] = tanhf(vv);
            }
        }
    }
}

__global__ __launch_bounds__(512, 1) void fused_kernel(
    const float* __restrict__ A, const float* __restrict__ x,
    const float* __restrict__ w1, const float* __restrict__ lw1, const float* __restrict__ lb1,
    const float* __restrict__ w2, const float* __restrict__ lw2, const float* __restrict__ lb2,
    const float* __restrict__ gw, const float* __restrict__ gb,
    const float* __restrict__ nw, const float* __restrict__ nb,
    const float* __restrict__ l3w, const float* __restrict__ l3b,
    const float* __restrict__ l4w, const float* __restrict__ l4b,
    const float* __restrict__ l5w, const float* __restrict__ l5b,
    float* __restrict__ h1ws, float* __restrict__ out)
{
    __shared__ __align__(16) char smem[153600];
    unsigned short* WbL = (unsigned short*)smem;            // 66,560 B (conv2 size)
    unsigned short* PbL = (unsigned short*)(smem + 66560);  // 87,040 B

    const int s = blockIdx.x, tid = threadIdx.x;
    const int wave = tid >> 6, lane = tid & 63;
    const int lm = lane & 15, kg = lane >> 4;
    const int i0 = wave * 16;

    float v[4][4];

    // ================= CONV1 =================
    conv_stage<CIN>(A, x, x, w1, lw1, lb1, WbL, PbL, s, tid, v);
    #pragma unroll
    for (int n = 0; n < 4; ++n)
        #pragma unroll
        for (int r = 0; r < 4; ++r)
            h1ws[((size_t)s * NN + i0 + kg * 4 + r) * HH + n * 16 + lm] = v[n][r];
    __syncthreads();   // h1 visible; PbL reads done -> conv2 may restage

    // ================= CONV2 =================
    conv_stage<YY>(A, x, h1ws, w2, lw2, lb2, WbL, PbL, s, tid, v);
    __syncthreads();   // PbL reads done -> alias LDS for pooling

    // ================= POOL + HEAD =================
    float* xc   = (float*)smem;            // [128][97] f32 = 49,664 B
    float* nws  = (float*)(smem + 49664);  // [96][128] f32 = 49,152 B
    float* gate = (float*)(smem + 98816);  // 512 B
    float* red  = (float*)(smem + 99328);  // 512 B
    float* tmp  = (float*)(smem + 99840);  // 512 B
    float* part = (float*)(smem + 100352); // [4][128] f32 = 2,048 B

    #pragma unroll
    for (int n = 0; n < 4; ++n)
        #pragma unroll
        for (int r = 0; r < 4; ++r)
            xc[(i0 + kg * 4 + r) * 97 + n * 16 + lm] = v[n][r];
    for (int t = tid; t < NN * CIN; t += 512)
        xc[(t >> 5) * 97 + 64 + (t & 31)] = x[(size_t)s * NN * CIN + t];
    for (int t = tid; t < YY * H3; t += 512)
        nws[t] = nw[t];
    __syncthreads();

    // gate softmax over nodes
    float z = 0.f, e = 0.f;
    if (tid < NN) {
        z = gb[0];
        for (int a = 0; a < YY; ++a) z += xc[tid * 97 + a] * gw[a];
        red[tid] = z;
    }
    __syncthreads();
    for (int off = 64; off > 0; off >>= 1) {
        if (tid < off) red[tid] = fmaxf(red[tid], red[tid + off]);
        __syncthreads();
    }
    const float zmax = red[0];
    __syncthreads();
    if (tid < NN) { e = expf(z - zmax); red[tid] = e; }
    __syncthreads();
    for (int off = 64; off > 0; off >>= 1) {
        if (tid < off) red[tid] += red[tid + off];
        __syncthreads();
    }
    const float gsum = red[0];
    __syncthreads();
    if (tid < NN) gate[tid] = e / gsum;
    __syncthreads();

    // pooled[b] = sum_i gate[i] * tanh(xc[i,:] @ nws[:,b] + nb[b]); 4 node-quarters
    {
        const int b = tid & 127, iq = tid >> 7;
        const float nbv = nb[b];
        float acc = 0.f;
        for (int i = iq * 32; i < iq * 32 + 32; i += 2) {
            float z0 = nbv, z1 = nbv;
            #pragma unroll 4
            for (int a = 0; a < YY; ++a) {
                float w = nws[a * H3 + b];
                z0 += xc[i * 97 + a] * w;
                z1 += xc[(i + 1) * 97 + a] * w;
            }
            acc += gate[i] * tanhf(z0) + gate[i + 1] * tanhf(z1);
        }
        part[tid] = acc;
    }
    __syncthreads();
    if (tid < H3) {
        float pooled = part[tid] + part[tid + 128] + part[tid + 256] + part[tid + 384];
        tmp[tid] = tanhf(pooled);             // h3
    }
    __syncthreads();
    if (tid < H3) {
        float a4 = l3b[tid];
        for (int aa = 0; aa < H3; ++aa) a4 += tmp[aa] * l3w[aa * H3 + tid];
        red[tid] = tanhf(a4);                 // h4
    }
    __syncthreads();
    if (tid < H4) {
        float a5 = l4b[tid];
        for (int aa = 0; aa < H3; ++aa) a5 += red[aa] * l4w[aa * H4 + tid];
        tmp[tid] = tanhf(a5);                 // h5
    }
    __syncthreads();
    if (tid == 0) {
        float zo = l5b[0];
        for (int aa = 0; aa < H4; ++aa) zo += tmp[aa] * l5w[aa];
        out[s] = 1.0f / (1.0f + expf(-zo));
    }
}

extern "C" void kernel_launch(void* const* d_in, const int* in_sizes, int n_in,
                              void* d_out, int out_size, void* d_ws, size_t ws_size,
                              hipStream_t stream)
{
    const float* A   = (const float*)d_in[0];
    const float* x   = (const float*)d_in[1];
    const float* w1  = (const float*)d_in[2];
    const float* lw1 = (const float*)d_in[3];
    const float* lb1 = (const float*)d_in[4];
    const float* w2  = (const float*)d_in[5];
    const float* lw2 = (const float*)d_in[6];
    const float* lb2 = (const float*)d_in[7];
    const float* gw  = (const float*)d_in[8];
    const float* gb  = (const float*)d_in[9];
    const float* nw  = (const float*)d_in[10];
    const float* nb  = (const float*)d_in[11];
    const float* l3w = (const float*)d_in[12];
    const float* l3b = (const float*)d_in[13];
    const float* l4w = (const float*)d_in[14];
    const float* l4b = (const float*)d_in[15];
    const float* l5w = (const float*)d_in[16];
    const float* l5b = (const float*)d_in[17];
    float* out = (float*)d_out;

    float* ws_h1 = (float*)d_ws;   // [512][128][64] f32

    fused_kernel<<<SN, 512, 0, stream>>>(A, x, w1, lw1, lb1, w2, lw2, lb2,
                                         gw, gb, nw, nb, l3w, l3b, l4w, l4b,
                                         l5w, l5b, ws_h1, out);
}

// Round 4
// 106.759 us; speedup vs baseline: 10.2458x; 1.8176x over previous
//
#include <hip/hip_runtime.h>
#include <math.h>

#define SN  512
#define NN  128
#define CIN 32
#define CA  5
#define HH  64
#define YY  96
#define H3  128
#define H4  64
#define EPSF 1e-7f

typedef __attribute__((ext_vector_type(8))) short  bf16x8;
typedef __attribute__((ext_vector_type(4))) float  f32x4;
typedef __attribute__((ext_vector_type(4))) unsigned short us4;

__device__ inline unsigned short f2b(float f) {
    unsigned u = __builtin_bit_cast(unsigned, f);
    return (unsigned short)((u + 0x7FFFu + ((u >> 16) & 1u)) >> 16);
}
__device__ inline float b2f(unsigned short h) {
    unsigned u = ((unsigned)h) << 16;
    return __builtin_bit_cast(float, u);
}
__device__ inline bf16x8 pack8(float4 f0, float4 f1) {
    bf16x8 v;
    v[0]=(short)f2b(f0.x); v[1]=(short)f2b(f0.y); v[2]=(short)f2b(f0.z); v[3]=(short)f2b(f0.w);
    v[4]=(short)f2b(f1.x); v[5]=(short)f2b(f1.y); v[6]=(short)f2b(f1.z); v[7]=(short)f2b(f1.w);
    return v;
}

// LDS layout (units: shorts):
//   WZ @ 0      : 5*64 rows * 104 = 33,280   (weights, bf16, c=4 is LW)
//   PZ @ 33280  : 4*64 rows * 136 = 34,816   (P = y@W_c, [c][b][j])
//   H1 @ 68096  : 128 rows * 72   =  9,216   (h1 bf16 [j][a])  -> total 154,624 B
#define WZ_OFF 0
#define PZ_OFF 33280
#define H1_OFF 68096

template<int CINY, bool FIRST>
__device__ __forceinline__ void conv_core(
    const float* __restrict__ xg,
    const float* __restrict__ W, const float* __restrict__ LW,
    const float* __restrict__ LB,
    short* SM, const bf16x8 (&Af)[4][4], float (&inv)[4][4],
    float (&v)[4][4], int tid)
{
    constexpr int K32 = CINY / 32;
    short* WZ = SM + WZ_OFF;
    short* PZ = SM + PZ_OFF;
    short* H1 = SM + H1_OFF;
    const int wave = tid >> 6, lane = tid & 63;
    const int lm = lane & 15, kg = lane >> 4;

    // ---- stage W[a][b][c] -> WZ[c][b][a] (rows 104), LW -> c=4 ----
    for (int t = tid; t < CINY*64*4; t += 512) {
        int c = t & 3, b = (t >> 2) & 63, a = t >> 8;
        WZ[(c*64 + b)*104 + a] = (short)f2b(W[t]);
    }
    for (int t = tid; t < CINY*64; t += 512) {
        int b = t & 63, a = t >> 6;
        WZ[(256 + b)*104 + a] = (short)f2b(LW[t]);
    }
    __syncthreads();

    // ---- P GEMM: P_c[j,b] = sum_a y[j,a] W_c[a,b]; wave owns j-tile ----
    f32x4 pc4[4];
    {
        const int jrow = wave*16 + lm;
        bf16x8 af[K32];
        if constexpr (CINY == 32) {
            float4 f0 = *(const float4*)(xg + jrow*CIN + kg*8);
            float4 f1 = *(const float4*)(xg + jrow*CIN + kg*8 + 4);
            af[0] = pack8(f0, f1);
        } else {
            af[0] = *(const bf16x8*)&H1[jrow*72 + kg*8];
            af[1] = *(const bf16x8*)&H1[jrow*72 + 32 + kg*8];
            float4 f0 = *(const float4*)(xg + jrow*CIN + kg*8);
            float4 f1 = *(const float4*)(xg + jrow*CIN + kg*8 + 4);
            af[2] = pack8(f0, f1);
        }
        #pragma unroll
        for (int c = 0; c < 5; ++c) {
            f32x4 pc[4];
            #pragma unroll
            for (int n = 0; n < 4; ++n) pc[n] = (f32x4){0.f,0.f,0.f,0.f};
            #pragma unroll
            for (int ks = 0; ks < K32; ++ks) {
                #pragma unroll
                for (int n = 0; n < 4; ++n) {
                    bf16x8 bw = *(const bf16x8*)&WZ[(c*64 + n*16 + lm)*104 + ks*32 + kg*8];
                    pc[n] = __builtin_amdgcn_mfma_f32_16x16x32_bf16(af[ks], bw, pc[n], 0,0,0);
                }
            }
            if (c < 4) {
                const int j0 = wave*16 + kg*4;
                #pragma unroll
                for (int n = 0; n < 4; ++n) {
                    us4 w;
                    w[0]=f2b(pc[n][0]); w[1]=f2b(pc[n][1]); w[2]=f2b(pc[n][2]); w[3]=f2b(pc[n][3]);
                    *(us4*)&PZ[(c*64 + n*16 + lm)*136 + j0] = w;
                }
            } else {
                #pragma unroll
                for (int n = 0; n < 4; ++n) pc4[n] = pc[n];  // linear term, f32
            }
        }
    }
    __syncthreads();

    // ---- main GEMM over A (register A-frags) + rowsum/normalize + tanh ----
    {
        f32x4 acc[4][4];
        #pragma unroll
        for (int c=0;c<4;++c)
            #pragma unroll
            for (int n=0;n<4;++n) acc[c][n] = (f32x4){0.f,0.f,0.f,0.f};
        f32x4 sums[4];
        if constexpr (FIRST) {
            #pragma unroll
            for (int c=0;c<4;++c) sums[c] = (f32x4){0.f,0.f,0.f,0.f};
        }
        bf16x8 ones;
        #pragma unroll
        for (int q=0;q<8;++q) ones[q] = (short)0x3F80;

        #pragma unroll
        for (int jt=0; jt<4; ++jt) {
            #pragma unroll
            for (int c=0;c<4;++c) {
                #pragma unroll
                for (int n=0;n<4;++n) {
                    bf16x8 bp = *(const bf16x8*)&PZ[(c*64 + n*16 + lm)*136 + jt*32 + kg*8];
                    acc[c][n] = __builtin_amdgcn_mfma_f32_16x16x32_bf16(Af[jt][c], bp, acc[c][n], 0,0,0);
                }
                if constexpr (FIRST)
                    sums[c] = __builtin_amdgcn_mfma_f32_16x16x32_bf16(Af[jt][c], ones, sums[c], 0,0,0);
            }
        }
        if constexpr (FIRST) {
            #pragma unroll
            for (int c=0;c<4;++c)
                #pragma unroll
                for (int r=0;r<4;++r) inv[c][r] = 1.0f/(sums[c][r] + EPSF);
        }
        #pragma unroll
        for (int n=0;n<4;++n) {
            const float lbv = LB[n*16 + lm];
            #pragma unroll
            for (int r=0;r<4;++r) {
                float vv = lbv + pc4[n][r];
                #pragma unroll
                for (int c=0;c<4;++c) vv += acc[c][n][r]*inv[c][r];
                v[n][r] = tanhf(vv);
            }
        }
    }
}

__global__ __launch_bounds__(512, 1) void fused_kernel(
    const float* __restrict__ A, const float* __restrict__ x,
    const float* __restrict__ w1, const float* __restrict__ lw1, const float* __restrict__ lb1,
    const float* __restrict__ w2, const float* __restrict__ lw2, const float* __restrict__ lb2,
    const float* __restrict__ gw, const float* __restrict__ gb,
    const float* __restrict__ nw, const float* __restrict__ nb,
    const float* __restrict__ l3w, const float* __restrict__ l3b,
    const float* __restrict__ l4w, const float* __restrict__ l4b,
    const float* __restrict__ l5w, const float* __restrict__ l5b,
    float* __restrict__ out)
{
    __shared__ __align__(16) char smem[154624];
    short* SM = (short*)smem;
    const int s = blockIdx.x, tid = threadIdx.x;
    const int wave = tid >> 6, lane = tid & 63;
    const int lm = lane & 15, kg = lane >> 4;
    const float* xg = x + (size_t)s*NN*CIN;

    // ===== Prepass: A -> bf16 MFMA fragments in registers (read once, coalesced) =====
    // Lane mapping per jt: row r = (lane>>3)+8*rh, 20 floats at l8*20 within the
    // 160-float (32j x 5c) stripe; e%5 / e/5 are compile-time (20*l8 ≡ 0 mod 5).
    bf16x8 Af[4][4];   // [jt][c]
    {
        short* L = SM + wave*2688;                 // wave-private [16][168]
        const float* Ab = A + ((size_t)s*NN + wave*16)*NN*CA;
        const int r8 = lane >> 3, l8 = lane & 7;
        #pragma unroll
        for (int jt=0; jt<4; ++jt) {
            #pragma unroll
            for (int rh=0; rh<2; ++rh) {
                const int r = r8 + rh*8;
                const float* rowp = Ab + (size_t)r*(NN*CA) + jt*160 + l8*20;
                short* lrow = L + r*168;
                #pragma unroll
                for (int it=0; it<10; ++it) {
                    float2 v2 = *(const float2*)(rowp + 2*it);
                    const int e0 = 2*it;
                    const int c0 = e0 % 5,      j0 = 4*l8 + e0/5;
                    const int c1 = (e0+1) % 5,  j1 = 4*l8 + (e0+1)/5;
                    if (c0 < 4) lrow[c0*40 + j0] = (short)f2b(v2.x);
                    if (c1 < 4) lrow[c1*40 + j1] = (short)f2b(v2.y);
                }
            }
            #pragma unroll
            for (int c=0;c<4;++c)
                Af[jt][c] = *(const bf16x8*)&L[lm*168 + c*40 + kg*8];
        }
    }
    __syncthreads();

    // ===== conv1 =====
    float inv[4][4];
    float v[4][4];
    conv_core<CIN, true>(xg, w1, lw1, lb1, SM, Af, inv, v, tid);

    // h1 -> LDS (bf16, [j][a] rows of 72)
    {
        short* H1 = SM + H1_OFF;
        #pragma unroll
        for (int n=0;n<4;++n)
            #pragma unroll
            for (int r=0;r<4;++r)
                H1[(wave*16 + kg*4 + r)*72 + n*16 + lm] = (short)f2b(v[n][r]);
    }

    // ===== conv2 (reuses A-frags and inv) =====
    conv_core<YY, false>(xg, w2, lw2, lb2, SM, Af, inv, v, tid);

    // ===== pool + head =====
    short* xcb = SM;                       // [128][104] bf16: [h2 | x]
    short* nwT = SM + 13312;               // [128][104] bf16: nw^T [b][a]
    float* part = (float*)(smem + 53248);  // [32][128]
    float* gate = (float*)(smem + 69632);  // 128 f32
    float* red  = (float*)(smem + 70144);  // 128 f32
    float* tmpv = (float*)(smem + 70656);  // 128 f32

    #pragma unroll
    for (int n=0;n<4;++n)
        #pragma unroll
        for (int r=0;r<4;++r)
            xcb[(wave*16 + kg*4 + r)*104 + n*16 + lm] = (short)f2b(v[n][r]);
    for (int t = tid; t < NN*CIN; t += 512)
        xcb[(t>>5)*104 + 64 + (t&31)] = (short)f2b(xg[t]);
    for (int t = tid; t < YY*H3; t += 512)
        nwT[(t&127)*104 + (t>>7)] = (short)f2b(nw[t]);
    __syncthreads();

    // gate softmax over nodes
    float z = 0.f, e = 0.f;
    if (tid < NN) {
        z = gb[0];
        for (int a = 0; a < YY; ++a) z += b2f((unsigned short)xcb[tid*104 + a]) * gw[a];
        red[tid] = z;
    }
    __syncthreads();
    for (int off = 64; off > 0; off >>= 1) {
        if (tid < off) red[tid] = fmaxf(red[tid], red[tid + off]);
        __syncthreads();
    }
    const float zmax = red[0];
    __syncthreads();
    if (tid < NN) { e = expf(z - zmax); red[tid] = e; }
    __syncthreads();
    for (int off = 64; off > 0; off >>= 1) {
        if (tid < off) red[tid] += red[tid + off];
        __syncthreads();
    }
    const float gsum = red[0];
    __syncthreads();
    if (tid < NN) gate[tid] = e / gsum;
    __syncthreads();

    // pooled GEMM via MFMA: out[i,b] = xc[i,:] @ nw[:,b]
    {
        f32x4 pacc[8];
        #pragma unroll
        for (int nt=0;nt<8;++nt) pacc[nt] = (f32x4){0.f,0.f,0.f,0.f};
        #pragma unroll
        for (int ks=0;ks<3;++ks) {
            bf16x8 afp = *(const bf16x8*)&xcb[(wave*16 + lm)*104 + ks*32 + kg*8];
            #pragma unroll
            for (int nt=0;nt<8;++nt) {
                bf16x8 bfp = *(const bf16x8*)&nwT[(nt*16 + lm)*104 + ks*32 + kg*8];
                pacc[nt] = __builtin_amdgcn_mfma_f32_16x16x32_bf16(afp, bfp, pacc[nt], 0,0,0);
            }
        }
        #pragma unroll
        for (int nt=0;nt<8;++nt) {
            const float nbv = nb[nt*16 + lm];
            float p = 0.f;
            #pragma unroll
            for (int r=0;r<4;++r) {
                const int i = wave*16 + kg*4 + r;
                p += gate[i] * tanhf(pacc[nt][r] + nbv);
            }
            part[(wave*4 + kg)*128 + nt*16 + lm] = p;
        }
    }
    __syncthreads();
    if (tid < H3) {
        float pooled = 0.f;
        #pragma unroll
        for (int g = 0; g < 32; ++g) pooled += part[g*128 + tid];
        tmpv[tid] = tanhf(pooled);                 // h3
    }
    __syncthreads();
    if (tid < H3) {
        float a4 = l3b[tid];
        for (int aa = 0; aa < H3; ++aa) a4 += tmpv[aa] * l3w[aa*H3 + tid];
        red[tid] = tanhf(a4);                      // h4
    }
    __syncthreads();
    if (tid < H4) {
        float a5 = l4b[tid];
        for (int aa = 0; aa < H3; ++aa) a5 += red[aa] * l4w[aa*H4 + tid];
        gate[tid] = tanhf(a5);                     // h5
    }
    __syncthreads();
    if (tid == 0) {
        float zo = l5b[0];
        for (int aa = 0; aa < H4; ++aa) zo += gate[aa] * l5w[aa];
        out[s] = 1.0f / (1.0f + expf(-zo));
    }
}

extern "C" void kernel_launch(void* const* d_in, const int* in_sizes, int n_in,
                              void* d_out, int out_size, void* d_ws, size_t ws_size,
                              hipStream_t stream)
{
    const float* A   = (const float*)d_in[0];
    const float* x   = (const float*)d_in[1];
    const float* w1  = (const float*)d_in[2];
    const float* lw1 = (const float*)d_in[3];
    const float* lb1 = (const float*)d_in[4];
    const float* w2  = (const float*)d_in[5];
    const float* lw2 = (const float*)d_in[6];
    const float* lb2 = (const float*)d_in[7];
    const float* gw  = (const float*)d_in[8];
    const float* gb  = (const float*)d_in[9];
    const float* nw  = (const float*)d_in[10];
    const float* nb  = (const float*)d_in[11];
    const float* l3w = (const float*)d_in[12];
    const float* l3b = (const float*)d_in[13];
    const float* l4w = (const float*)d_in[14];
    const float* l4b = (const float*)d_in[15];
    const float* l5w = (const float*)d_in[16];
    const float* l5b = (const float*)d_in[17];
    float* out = (float*)d_out;

    fused_kernel<<<SN, 512, 0, stream>>>(A, x, w1, lw1, lb1, w2, lw2, lb2,
                                         gw, gb, nw, nb, l3w, l3b, l4w, l4b,
                                         l5w, l5b, out);
}